// Round 1
// baseline (360.523 us; speedup 1.0000x reference)
//
#include <hip/hip_runtime.h>
#include <cstdint>

typedef unsigned short u16;
typedef short bf16x8_t __attribute__((ext_vector_type(8)));
typedef float f32x4_t __attribute__((ext_vector_type(4)));

#define DEVFN __device__ __forceinline__

DEVFN u16 f2bf(float f) {
  unsigned u = __builtin_bit_cast(unsigned, f);
  u = (u + 0x7fffu + ((u >> 16) & 1u)) >> 16;
  return (u16)u;
}
DEVFN float bf2f(u16 s) {
  unsigned u = ((unsigned)s) << 16;
  return __builtin_bit_cast(float, u);
}
DEVFN float lrelu(float x) { return x > 0.f ? x : 0.2f * x; }

// ---------------- converts ----------------
__global__ void f32_to_bf16_kernel(const float* __restrict__ in, u16* __restrict__ out, long n) {
  long i = ((long)blockIdx.x * 256 + threadIdx.x) * 4;
  if (i + 4 <= n) {
    float4 v = *reinterpret_cast<const float4*>(in + i);
    uint2 pack;
    pack.x = (unsigned)f2bf(v.x) | ((unsigned)f2bf(v.y) << 16);
    pack.y = (unsigned)f2bf(v.z) | ((unsigned)f2bf(v.w) << 16);
    *reinterpret_cast<uint2*>(out + i) = pack;
  }
}

// in [K][M] row-major -> out [M][K] bf16
__global__ void conv_transpose_kernel(const float* __restrict__ in, u16* __restrict__ out, int K, int M) {
  int idx = blockIdx.x * 256 + threadIdx.x;
  if (idx >= K * M) return;
  int k = idx / M, m = idx % M;
  out[(size_t)m * K + k] = f2bf(in[idx]);
}

// ---------------- GEMM: A[M][K] bf16 @ BT[N][K] bf16 -> C[M][N] bf16 ----------------
template<int BM, int BN, int WROWS, int WCOLS>
__global__ __launch_bounds__(256) void gemm_bf16_kernel(
    const u16* __restrict__ A, const u16* __restrict__ BT, u16* __restrict__ C,
    int M, int N, int K)
{
  constexpr int BK = 32;
  constexpr int WM = BM / WROWS;
  constexpr int WN = BN / WCOLS;
  constexpr int MF = WM / 16;
  constexpr int NF = WN / 16;
  __shared__ __align__(16) u16 sA[BM][BK];
  __shared__ __align__(16) u16 sB[BN][BK];

  const int tid = threadIdx.x;
  const int lane = tid & 63;
  const int wid = tid >> 6;
  const int wr = wid / WCOLS, wc = wid % WCOLS;
  const int brow = blockIdx.x * BM;
  const int bcol = blockIdx.y * BN;

  f32x4_t acc[MF][NF];
#pragma unroll
  for (int i = 0; i < MF; ++i)
#pragma unroll
    for (int j = 0; j < NF; ++j) acc[i][j] = f32x4_t{0.f, 0.f, 0.f, 0.f};

  const int rsel = lane & 15;
  const int kgrp = (lane >> 4) * 8;

  for (int k0 = 0; k0 < K; k0 += BK) {
#pragma unroll
    for (int c = 0; c < BM * BK / (8 * 256); ++c) {
      int idx = (tid + c * 256) * 8;
      int row = idx >> 5, col = idx & 31;
      int gr = brow + row; gr = gr < M ? gr : M - 1;
      *reinterpret_cast<uint4*>(&sA[row][col]) =
          *reinterpret_cast<const uint4*>(A + (size_t)gr * K + (k0 + col));
    }
#pragma unroll
    for (int c = 0; c < BN * BK / (8 * 256); ++c) {
      int idx = (tid + c * 256) * 8;
      int row = idx >> 5, col = idx & 31;
      *reinterpret_cast<uint4*>(&sB[row][col]) =
          *reinterpret_cast<const uint4*>(BT + (size_t)(bcol + row) * K + (k0 + col));
    }
    __syncthreads();
    bf16x8_t af[MF], bfr[NF];
#pragma unroll
    for (int i = 0; i < MF; ++i)
      af[i] = *reinterpret_cast<const bf16x8_t*>(&sA[wr * WM + i * 16 + rsel][kgrp]);
#pragma unroll
    for (int j = 0; j < NF; ++j)
      bfr[j] = *reinterpret_cast<const bf16x8_t*>(&sB[wc * WN + j * 16 + rsel][kgrp]);
#pragma unroll
    for (int i = 0; i < MF; ++i)
#pragma unroll
      for (int j = 0; j < NF; ++j)
        acc[i][j] = __builtin_amdgcn_mfma_f32_16x16x32_bf16(af[i], bfr[j], acc[i][j], 0, 0, 0);
    __syncthreads();
  }

  const int crow0 = (lane >> 4) * 4;
  const int ccol = lane & 15;
#pragma unroll
  for (int i = 0; i < MF; ++i)
#pragma unroll
    for (int j = 0; j < NF; ++j)
#pragma unroll
      for (int r = 0; r < 4; ++r) {
        int gr = brow + wr * WM + i * 16 + crow0 + r;
        int gc = bcol + wc * WN + j * 16 + ccol;
        if (gr < M) C[(size_t)gr * N + gc] = f2bf(acc[i][j][r]);
      }
}

// ---------------- alpha dots ----------------
// layer1: h[N][512] bf16, heads=4, D=128
__global__ __launch_bounds__(256) void alpha1_kernel(
    const u16* __restrict__ h1, const float* __restrict__ a_s, const float* __restrict__ a_d,
    float* __restrict__ as1, float* __restrict__ ad1, int n)
{
  int node = (blockIdx.x * 256 + threadIdx.x) >> 6;
  int lane = threadIdx.x & 63;
  if (node >= n) return;
  int head = lane >> 4;
  int d0 = (lane & 15) * 8;
  bf16x8_t hv = *reinterpret_cast<const bf16x8_t*>(h1 + (size_t)node * 512 + lane * 8);
  const float* asrow = a_s + head * 128 + d0;
  const float* adrow = a_d + head * 128 + d0;
  float ps = 0.f, pd = 0.f;
#pragma unroll
  for (int j = 0; j < 8; ++j) {
    float v = bf2f((u16)hv[j]);
    ps = fmaf(v, asrow[j], ps);
    pd = fmaf(v, adrow[j], pd);
  }
#pragma unroll
  for (int d = 1; d < 16; d <<= 1) {
    ps += __shfl_xor(ps, d, 64);
    pd += __shfl_xor(pd, d, 64);
  }
  if ((lane & 15) == 0) {
    as1[(size_t)node * 4 + head] = ps;
    ad1[(size_t)node * 4 + head] = pd;
  }
}

// layer2: h[N][64] bf16, 1 head, D=64
__global__ __launch_bounds__(256) void alpha2_kernel(
    const u16* __restrict__ h2, const float* __restrict__ a_s, const float* __restrict__ a_d,
    float* __restrict__ as2, float* __restrict__ ad2, int n)
{
  int node = (blockIdx.x * 256 + threadIdx.x) >> 6;
  int lane = threadIdx.x & 63;
  if (node >= n) return;
  float v = bf2f(h2[(size_t)node * 64 + lane]);
  float ps = v * a_s[lane], pd = v * a_d[lane];
#pragma unroll
  for (int d = 1; d < 64; d <<= 1) {
    ps += __shfl_xor(ps, d, 64);
    pd += __shfl_xor(pd, d, 64);
  }
  if (lane == 0) { as2[node] = ps; ad2[node] = pd; }
}

// ---------------- CSR build ----------------
__global__ void deg_kernel(const int* __restrict__ dst, int* __restrict__ cnt, int e) {
  int i = blockIdx.x * 256 + threadIdx.x;
  if (i < e) atomicAdd(&cnt[dst[i]], 1);
}

DEVFN int block_scan_256(int v, int tid, int* wsum) {
#pragma unroll
  for (int d = 1; d < 64; d <<= 1) {
    int u = __shfl_up(v, d, 64);
    if ((tid & 63) >= d) v += u;
  }
  if ((tid & 63) == 63) wsum[tid >> 6] = v;
  __syncthreads();
  int add = 0;
#pragma unroll
  for (int w = 0; w < 4; ++w) add += (w < (tid >> 6)) ? wsum[w] : 0;
  __syncthreads();
  return v + add;
}

__global__ __launch_bounds__(256) void scan_a_kernel(const int* __restrict__ cnt, int* __restrict__ bsum, int n) {
  __shared__ int ws4[4];
  int i = blockIdx.x * 256 + threadIdx.x;
  int v = (i < n) ? cnt[i] + 1 : 0;   // +1 self loop
  int incl = block_scan_256(v, threadIdx.x, ws4);
  if (threadIdx.x == 255) bsum[blockIdx.x] = incl;
}

__global__ __launch_bounds__(256) void scan_b_kernel(const int* __restrict__ bsum, int* __restrict__ boff, int nb) {
  __shared__ int ws4[4];
  int v = (threadIdx.x < nb) ? bsum[threadIdx.x] : 0;
  int incl = block_scan_256(v, threadIdx.x, ws4);
  if (threadIdx.x < nb) boff[threadIdx.x] = incl - v;
}

__global__ __launch_bounds__(256) void scan_c_kernel(
    const int* __restrict__ cnt, const int* __restrict__ boff,
    int* __restrict__ rowoff, int* __restrict__ cursor, int n)
{
  __shared__ int ws4[4];
  int i = blockIdx.x * 256 + threadIdx.x;
  int v = (i < n) ? cnt[i] + 1 : 0;
  int incl = block_scan_256(v, threadIdx.x, ws4);
  int excl = incl - v;
  int off = boff[blockIdx.x] + excl;
  if (i < n) {
    rowoff[i] = off;
    cursor[i] = off;
    if (i == n - 1) rowoff[n] = off + v;
  }
}

__global__ void scatter_kernel(const int* __restrict__ srcs, const int* __restrict__ dsts,
                               int* __restrict__ cursor, int* __restrict__ csr, int e, int n) {
  int i = blockIdx.x * 256 + threadIdx.x;
  if (i >= e + n) return;
  int s, d;
  if (i < e) { s = srcs[i]; d = dsts[i]; }
  else       { s = i - e; d = s; }
  int pos = atomicAdd(&cursor[d], 1);
  csr[pos] = s;
}

// ---------------- aggregation ----------------
// layer1: one wave per dst node. lane covers dims [lane*8, lane*8+8), head = lane>>4.
__global__ __launch_bounds__(256) void agg1_kernel(
    const u16* __restrict__ h1, const float* __restrict__ as1, const float* __restrict__ ad1,
    const int* __restrict__ rowoff, const int* __restrict__ csr,
    const float* __restrict__ b1, u16* __restrict__ out, int n)
{
  int node = (blockIdx.x * 256 + threadIdx.x) >> 6;
  int lane = threadIdx.x & 63;
  if (node >= n) return;
  int head = lane >> 4;
  float4 adv = *reinterpret_cast<const float4*>(ad1 + (size_t)node * 4);
  int e0 = rowoff[node], e1 = rowoff[node + 1];

  float4 m = make_float4(-1e30f, -1e30f, -1e30f, -1e30f);
  for (int e = e0; e < e1; ++e) {
    int s = csr[e];
    float4 a = *reinterpret_cast<const float4*>(as1 + (size_t)s * 4);
    m.x = fmaxf(m.x, lrelu(a.x + adv.x));
    m.y = fmaxf(m.y, lrelu(a.y + adv.y));
    m.z = fmaxf(m.z, lrelu(a.z + adv.z));
    m.w = fmaxf(m.w, lrelu(a.w + adv.w));
  }

  float4 den = make_float4(0.f, 0.f, 0.f, 0.f);
  float acc[8];
#pragma unroll
  for (int j = 0; j < 8; ++j) acc[j] = 0.f;
  const int dimbase = lane * 8;

  for (int e = e0; e < e1; ++e) {
    int s = csr[e];
    float4 a = *reinterpret_cast<const float4*>(as1 + (size_t)s * 4);
    float ex0 = expf(lrelu(a.x + adv.x) - m.x); den.x += ex0;
    float ex1 = expf(lrelu(a.y + adv.y) - m.y); den.y += ex1;
    float ex2 = expf(lrelu(a.z + adv.z) - m.z); den.z += ex2;
    float ex3 = expf(lrelu(a.w + adv.w) - m.w); den.w += ex3;
    float w = head == 0 ? ex0 : head == 1 ? ex1 : head == 2 ? ex2 : ex3;
    bf16x8_t hv = *reinterpret_cast<const bf16x8_t*>(h1 + (size_t)s * 512 + dimbase);
#pragma unroll
    for (int j = 0; j < 8; ++j) acc[j] = fmaf(w, bf2f((u16)hv[j]), acc[j]);
  }

  float dh = (head == 0 ? den.x : head == 1 ? den.y : head == 2 ? den.z : den.w) + 1e-16f;
  float inv = 1.f / dh;
  u16* orow = out + (size_t)node * 512 + dimbase;
#pragma unroll
  for (int j = 0; j < 8; ++j) {
    float v = acc[j] * inv + b1[dimbase + j];
    v = v > 0.f ? v : expm1f(v);   // ELU between layers
    orow[j] = f2bf(v);
  }
}

// layer2: one wave per dst node, 64 dims, 1 head. Output f32 (+b2), no ELU.
__global__ __launch_bounds__(256) void agg2_kernel(
    const u16* __restrict__ h2, const float* __restrict__ as2, const float* __restrict__ ad2,
    const int* __restrict__ rowoff, const int* __restrict__ csr,
    const float* __restrict__ b2, float* __restrict__ out, int n)
{
  int node = (blockIdx.x * 256 + threadIdx.x) >> 6;
  int lane = threadIdx.x & 63;
  if (node >= n) return;
  float adv = ad2[node];
  int e0 = rowoff[node], e1 = rowoff[node + 1];

  float m = -1e30f;
  for (int e = e0; e < e1; ++e) {
    float a = as2[csr[e]];
    m = fmaxf(m, lrelu(a + adv));
  }
  float den = 0.f, acc = 0.f;
  for (int e = e0; e < e1; ++e) {
    int s = csr[e];
    float ex = expf(lrelu(as2[s] + adv) - m);
    den += ex;
    acc = fmaf(ex, bf2f(h2[(size_t)s * 64 + lane]), acc);
  }
  out[(size_t)node * 64 + lane] = acc / (den + 1e-16f) + b2[lane];
}

// ---------------- launch ----------------
extern "C" void kernel_launch(void* const* d_in, const int* in_sizes, int n_in,
                              void* d_out, int out_size, void* d_ws, size_t ws_size,
                              hipStream_t stream) {
  const float* x   = (const float*)d_in[0];
  const int*   ei  = (const int*)d_in[1];
  const float* W1  = (const float*)d_in[3];
  const float* a1s = (const float*)d_in[4];
  const float* a1d = (const float*)d_in[5];
  const float* b1  = (const float*)d_in[6];
  const float* W2  = (const float*)d_in[7];
  const float* a2s = (const float*)d_in[8];
  const float* a2d = (const float*)d_in[9];
  const float* b2  = (const float*)d_in[10];
  float* out = (float*)d_out;

  const int IN_DIM = 256, H1D1 = 512, D2 = 64;
  const int N = in_sizes[0] / IN_DIM;
  const int E = in_sizes[1] / 2;

  char* ws = (char*)d_ws;
  size_t off = 0;
  auto alloc = [&](size_t bytes) -> void* {
    void* p = ws + off;
    off += (bytes + 255) & ~(size_t)255;
    return p;
  };
  u16*  xb     = (u16*)alloc((size_t)N * IN_DIM * 2);
  u16*  w1t    = (u16*)alloc((size_t)H1D1 * IN_DIM * 2);
  u16*  w2t    = (u16*)alloc((size_t)D2 * H1D1 * 2);
  u16*  h1b    = (u16*)alloc((size_t)N * H1D1 * 2);
  float* as1   = (float*)alloc((size_t)N * 4 * 4);
  float* ad1   = (float*)alloc((size_t)N * 4 * 4);
  int*  cnt    = (int*)alloc((size_t)N * 4);
  int*  cursor = (int*)alloc((size_t)N * 4);
  int*  rowoff = (int*)alloc((size_t)(N + 1) * 4);
  int*  bsum   = (int*)alloc(256 * 4);
  int*  boff   = (int*)alloc(256 * 4);
  int*  csr    = (int*)alloc((size_t)(E + N) * 4);
  u16*  h1o    = (u16*)alloc((size_t)N * H1D1 * 2);
  u16*  h2b    = (u16*)alloc((size_t)N * D2 * 2);
  float* as2   = (float*)alloc((size_t)N * 4);
  float* ad2   = (float*)alloc((size_t)N * 4);
  (void)n_in; (void)out_size; (void)ws_size;

  const int* esrc = ei;
  const int* edst = ei + E;

  hipMemsetAsync(cnt, 0, (size_t)N * 4, stream);

  f32_to_bf16_kernel<<<((long)N * IN_DIM / 4 + 255) / 256, 256, 0, stream>>>(x, xb, (long)N * IN_DIM);
  conv_transpose_kernel<<<(IN_DIM * H1D1 + 255) / 256, 256, 0, stream>>>(W1, w1t, IN_DIM, H1D1);
  conv_transpose_kernel<<<(H1D1 * D2 + 255) / 256, 256, 0, stream>>>(W2, w2t, H1D1, D2);

  dim3 g1((N + 127) / 128, H1D1 / 128);
  gemm_bf16_kernel<128, 128, 2, 2><<<g1, 256, 0, stream>>>(xb, w1t, h1b, N, H1D1, IN_DIM);

  alpha1_kernel<<<(N + 3) / 4, 256, 0, stream>>>(h1b, a1s, a1d, as1, ad1, N);

  deg_kernel<<<(E + 255) / 256, 256, 0, stream>>>(edst, cnt, E);
  int nsb = (N + 255) / 256;
  scan_a_kernel<<<nsb, 256, 0, stream>>>(cnt, bsum, N);
  scan_b_kernel<<<1, 256, 0, stream>>>(bsum, boff, nsb);
  scan_c_kernel<<<nsb, 256, 0, stream>>>(cnt, boff, rowoff, cursor, N);
  scatter_kernel<<<(E + N + 255) / 256, 256, 0, stream>>>(esrc, edst, cursor, csr, E, N);

  agg1_kernel<<<(N + 3) / 4, 256, 0, stream>>>(h1b, as1, ad1, rowoff, csr, b1, h1o, N);

  dim3 g2((N + 127) / 128, 1);
  gemm_bf16_kernel<128, 64, 4, 1><<<g2, 256, 0, stream>>>(h1o, w2t, h2b, N, D2, H1D1);

  alpha2_kernel<<<(N + 3) / 4, 256, 0, stream>>>(h2b, a2s, a2d, as2, ad2, N);
  agg2_kernel<<<(N + 3) / 4, 256, 0, stream>>>(h2b, as2, ad2, rowoff, csr, b2, out, N);
}

// Round 2
// 303.419 us; speedup vs baseline: 1.1882x; 1.1882x over previous
//
#include <hip/hip_runtime.h>
#include <cstdint>

typedef unsigned short u16;
typedef short bf16x8_t __attribute__((ext_vector_type(8)));
typedef float f32x4_t __attribute__((ext_vector_type(4)));

#define DEVFN __device__ __forceinline__

DEVFN u16 f2bf(float f) {
  unsigned u = __builtin_bit_cast(unsigned, f);
  u = (u + 0x7fffu + ((u >> 16) & 1u)) >> 16;
  return (u16)u;
}
DEVFN float bf2f(u16 s) {
  unsigned u = ((unsigned)s) << 16;
  return __builtin_bit_cast(float, u);
}
DEVFN float lrelu(float x) { return x > 0.f ? x : 0.2f * x; }

// ---------------- converts ----------------
__global__ void f32_to_bf16_kernel(const float* __restrict__ in, u16* __restrict__ out, long n) {
  long i = ((long)blockIdx.x * 256 + threadIdx.x) * 4;
  if (i + 4 <= n) {
    float4 v = *reinterpret_cast<const float4*>(in + i);
    uint2 pack;
    pack.x = (unsigned)f2bf(v.x) | ((unsigned)f2bf(v.y) << 16);
    pack.y = (unsigned)f2bf(v.z) | ((unsigned)f2bf(v.w) << 16);
    *reinterpret_cast<uint2*>(out + i) = pack;
  }
}

// in [K][M] row-major -> out [M][K] bf16
__global__ void conv_transpose_kernel(const float* __restrict__ in, u16* __restrict__ out, int K, int M) {
  int idx = blockIdx.x * 256 + threadIdx.x;
  if (idx >= K * M) return;
  int k = idx / M, m = idx % M;
  out[(size_t)m * K + k] = f2bf(in[idx]);
}

// ---------------- GEMM: A[M][K] bf16 @ BT[N][K] bf16 -> C[M][N] bf16 ----------------
template<int BM, int BN, int WROWS, int WCOLS>
__global__ __launch_bounds__(256) void gemm_bf16_kernel(
    const u16* __restrict__ A, const u16* __restrict__ BT, u16* __restrict__ C,
    int M, int N, int K)
{
  constexpr int BK = 32;
  constexpr int WM = BM / WROWS;
  constexpr int WN = BN / WCOLS;
  constexpr int MF = WM / 16;
  constexpr int NF = WN / 16;
  __shared__ __align__(16) u16 sA[BM][BK];
  __shared__ __align__(16) u16 sB[BN][BK];

  const int tid = threadIdx.x;
  const int lane = tid & 63;
  const int wid = tid >> 6;
  const int wr = wid / WCOLS, wc = wid % WCOLS;
  const int brow = blockIdx.x * BM;
  const int bcol = blockIdx.y * BN;

  f32x4_t acc[MF][NF];
#pragma unroll
  for (int i = 0; i < MF; ++i)
#pragma unroll
    for (int j = 0; j < NF; ++j) acc[i][j] = f32x4_t{0.f, 0.f, 0.f, 0.f};

  const int rsel = lane & 15;
  const int kgrp = (lane >> 4) * 8;

  for (int k0 = 0; k0 < K; k0 += BK) {
#pragma unroll
    for (int c = 0; c < BM * BK / (8 * 256); ++c) {
      int idx = (tid + c * 256) * 8;
      int row = idx >> 5, col = idx & 31;
      int gr = brow + row; gr = gr < M ? gr : M - 1;
      *reinterpret_cast<uint4*>(&sA[row][col]) =
          *reinterpret_cast<const uint4*>(A + (size_t)gr * K + (k0 + col));
    }
#pragma unroll
    for (int c = 0; c < BN * BK / (8 * 256); ++c) {
      int idx = (tid + c * 256) * 8;
      int row = idx >> 5, col = idx & 31;
      *reinterpret_cast<uint4*>(&sB[row][col]) =
          *reinterpret_cast<const uint4*>(BT + (size_t)(bcol + row) * K + (k0 + col));
    }
    __syncthreads();
    bf16x8_t af[MF], bfr[NF];
#pragma unroll
    for (int i = 0; i < MF; ++i)
      af[i] = *reinterpret_cast<const bf16x8_t*>(&sA[wr * WM + i * 16 + rsel][kgrp]);
#pragma unroll
    for (int j = 0; j < NF; ++j)
      bfr[j] = *reinterpret_cast<const bf16x8_t*>(&sB[wc * WN + j * 16 + rsel][kgrp]);
#pragma unroll
    for (int i = 0; i < MF; ++i)
#pragma unroll
      for (int j = 0; j < NF; ++j)
        acc[i][j] = __builtin_amdgcn_mfma_f32_16x16x32_bf16(af[i], bfr[j], acc[i][j], 0, 0, 0);
    __syncthreads();
  }

  const int crow0 = (lane >> 4) * 4;
  const int ccol = lane & 15;
#pragma unroll
  for (int i = 0; i < MF; ++i)
#pragma unroll
    for (int j = 0; j < NF; ++j)
#pragma unroll
      for (int r = 0; r < 4; ++r) {
        int gr = brow + wr * WM + i * 16 + crow0 + r;
        int gc = bcol + wc * WN + j * 16 + ccol;
        if (gr < M) C[(size_t)gr * N + gc] = f2bf(acc[i][j][r]);
      }
}

// ---------------- alpha dots ----------------
// layer1: h[N][512] bf16, heads=4, D=128
__global__ __launch_bounds__(256) void alpha1_kernel(
    const u16* __restrict__ h1, const float* __restrict__ a_s, const float* __restrict__ a_d,
    float* __restrict__ as1, float* __restrict__ ad1, int n)
{
  int node = (blockIdx.x * 256 + threadIdx.x) >> 6;
  int lane = threadIdx.x & 63;
  if (node >= n) return;
  int head = lane >> 4;
  int d0 = (lane & 15) * 8;
  bf16x8_t hv = *reinterpret_cast<const bf16x8_t*>(h1 + (size_t)node * 512 + lane * 8);
  const float* asrow = a_s + head * 128 + d0;
  const float* adrow = a_d + head * 128 + d0;
  float ps = 0.f, pd = 0.f;
#pragma unroll
  for (int j = 0; j < 8; ++j) {
    float v = bf2f((u16)hv[j]);
    ps = fmaf(v, asrow[j], ps);
    pd = fmaf(v, adrow[j], pd);
  }
#pragma unroll
  for (int d = 1; d < 16; d <<= 1) {
    ps += __shfl_xor(ps, d, 64);
    pd += __shfl_xor(pd, d, 64);
  }
  if ((lane & 15) == 0) {
    as1[(size_t)node * 4 + head] = ps;
    ad1[(size_t)node * 4 + head] = pd;
  }
}

// layer2: h[N][64] bf16, 1 head, D=64
__global__ __launch_bounds__(256) void alpha2_kernel(
    const u16* __restrict__ h2, const float* __restrict__ a_s, const float* __restrict__ a_d,
    float* __restrict__ as2, float* __restrict__ ad2, int n)
{
  int node = (blockIdx.x * 256 + threadIdx.x) >> 6;
  int lane = threadIdx.x & 63;
  if (node >= n) return;
  float v = bf2f(h2[(size_t)node * 64 + lane]);
  float ps = v * a_s[lane], pd = v * a_d[lane];
#pragma unroll
  for (int d = 1; d < 64; d <<= 1) {
    ps += __shfl_xor(ps, d, 64);
    pd += __shfl_xor(pd, d, 64);
  }
  if (lane == 0) { as2[node] = ps; ad2[node] = pd; }
}

// ---------------- CSR build ----------------
__global__ void deg_kernel(const int* __restrict__ dst, int* __restrict__ cnt, int e) {
  int i = blockIdx.x * 256 + threadIdx.x;
  if (i < e) atomicAdd(&cnt[dst[i]], 1);
}

DEVFN int block_scan_256(int v, int tid, int* wsum) {
#pragma unroll
  for (int d = 1; d < 64; d <<= 1) {
    int u = __shfl_up(v, d, 64);
    if ((tid & 63) >= d) v += u;
  }
  if ((tid & 63) == 63) wsum[tid >> 6] = v;
  __syncthreads();
  int add = 0;
#pragma unroll
  for (int w = 0; w < 4; ++w) add += (w < (tid >> 6)) ? wsum[w] : 0;
  __syncthreads();
  return v + add;
}

__global__ __launch_bounds__(256) void scan_a_kernel(const int* __restrict__ cnt, int* __restrict__ bsum, int n) {
  __shared__ int ws4[4];
  int i = blockIdx.x * 256 + threadIdx.x;
  int v = (i < n) ? cnt[i] + 1 : 0;   // +1 self loop
  int incl = block_scan_256(v, threadIdx.x, ws4);
  if (threadIdx.x == 255) bsum[blockIdx.x] = incl;
}

__global__ __launch_bounds__(256) void scan_b_kernel(const int* __restrict__ bsum, int* __restrict__ boff, int nb) {
  __shared__ int ws4[4];
  int v = (threadIdx.x < nb) ? bsum[threadIdx.x] : 0;
  int incl = block_scan_256(v, threadIdx.x, ws4);
  if (threadIdx.x < nb) boff[threadIdx.x] = incl - v;
}

__global__ __launch_bounds__(256) void scan_c_kernel(
    const int* __restrict__ cnt, const int* __restrict__ boff,
    int* __restrict__ rowoff, int* __restrict__ cursor, int n)
{
  __shared__ int ws4[4];
  int i = blockIdx.x * 256 + threadIdx.x;
  int v = (i < n) ? cnt[i] + 1 : 0;
  int incl = block_scan_256(v, threadIdx.x, ws4);
  int excl = incl - v;
  int off = boff[blockIdx.x] + excl;
  if (i < n) {
    rowoff[i] = off;
    cursor[i] = off;
    if (i == n - 1) rowoff[n] = off + v;
  }
}

__global__ void scatter_kernel(const int* __restrict__ srcs, const int* __restrict__ dsts,
                               int* __restrict__ cursor, int* __restrict__ csr, int e, int n) {
  int i = blockIdx.x * 256 + threadIdx.x;
  if (i >= e + n) return;
  int s, d;
  if (i < e) { s = srcs[i]; d = dsts[i]; }
  else       { s = i - e; d = s; }
  int pos = atomicAdd(&cursor[d], 1);
  csr[pos] = s;
}

// ---------------- softmax (per-node, hoisted out of the gather) ----------------
// layer1: one THREAD per node, 4 heads vectorized. Writes unnormalized ex per
// CSR slot to alpha[(E+N)*4] and 1/(den+eps) per (node,head) to invden.
__global__ __launch_bounds__(256) void softmax1_kernel(
    const float* __restrict__ as1, const float* __restrict__ ad1,
    const int* __restrict__ rowoff, const int* __restrict__ csr,
    float* __restrict__ alpha, float* __restrict__ invden, int n)
{
  int node = blockIdx.x * 256 + threadIdx.x;
  if (node >= n) return;
  float4 adv = *reinterpret_cast<const float4*>(ad1 + (size_t)node * 4);
  int e0 = rowoff[node], e1 = rowoff[node + 1];

  float4 m = make_float4(-1e30f, -1e30f, -1e30f, -1e30f);
  for (int e = e0; e < e1; ++e) {
    int s = csr[e];
    float4 a = *reinterpret_cast<const float4*>(as1 + (size_t)s * 4);
    m.x = fmaxf(m.x, lrelu(a.x + adv.x));
    m.y = fmaxf(m.y, lrelu(a.y + adv.y));
    m.z = fmaxf(m.z, lrelu(a.z + adv.z));
    m.w = fmaxf(m.w, lrelu(a.w + adv.w));
  }
  float4 den = make_float4(0.f, 0.f, 0.f, 0.f);
  for (int e = e0; e < e1; ++e) {
    int s = csr[e];
    float4 a = *reinterpret_cast<const float4*>(as1 + (size_t)s * 4);
    float4 ex;
    ex.x = expf(lrelu(a.x + adv.x) - m.x); den.x += ex.x;
    ex.y = expf(lrelu(a.y + adv.y) - m.y); den.y += ex.y;
    ex.z = expf(lrelu(a.z + adv.z) - m.z); den.z += ex.z;
    ex.w = expf(lrelu(a.w + adv.w) - m.w); den.w += ex.w;
    *reinterpret_cast<float4*>(alpha + (size_t)e * 4) = ex;
  }
  float4 inv;
  inv.x = 1.f / (den.x + 1e-16f);
  inv.y = 1.f / (den.y + 1e-16f);
  inv.z = 1.f / (den.z + 1e-16f);
  inv.w = 1.f / (den.w + 1e-16f);
  *reinterpret_cast<float4*>(invden + (size_t)node * 4) = inv;
}

// layer2: one thread per node, scalar (1 head)
__global__ __launch_bounds__(256) void softmax2_kernel(
    const float* __restrict__ as2, const float* __restrict__ ad2,
    const int* __restrict__ rowoff, const int* __restrict__ csr,
    float* __restrict__ alpha, float* __restrict__ invden, int n)
{
  int node = blockIdx.x * 256 + threadIdx.x;
  if (node >= n) return;
  float adv = ad2[node];
  int e0 = rowoff[node], e1 = rowoff[node + 1];
  float m = -1e30f;
  for (int e = e0; e < e1; ++e)
    m = fmaxf(m, lrelu(as2[csr[e]] + adv));
  float den = 0.f;
  for (int e = e0; e < e1; ++e) {
    float ex = expf(lrelu(as2[csr[e]] + adv) - m);
    den += ex;
    alpha[e] = ex;
  }
  invden[node] = 1.f / (den + 1e-16f);
}

// ---------------- aggregation (pure weighted gather now) ----------------
// layer1: one wave per dst node. lane covers dims [lane*8, lane*8+8), head = lane>>4.
__global__ __launch_bounds__(256) void agg1_kernel(
    const u16* __restrict__ h1, const float* __restrict__ alpha,
    const float* __restrict__ invden, const int* __restrict__ rowoff,
    const int* __restrict__ csr, const float* __restrict__ b1,
    u16* __restrict__ out, int n)
{
  int node = (blockIdx.x * 256 + threadIdx.x) >> 6;
  int lane = threadIdx.x & 63;
  if (node >= n) return;
  int head = lane >> 4;
  const int dimbase = lane * 8;
  int e0 = rowoff[node], e1 = rowoff[node + 1];

  float acc[8];
#pragma unroll
  for (int j = 0; j < 8; ++j) acc[j] = 0.f;

  int s = (e0 < e1) ? csr[e0] : 0;
  for (int e = e0; e < e1; ++e) {
    int snext = (e + 1 < e1) ? csr[e + 1] : s;
    float w = alpha[(size_t)e * 4 + head];
    bf16x8_t hv = *reinterpret_cast<const bf16x8_t*>(h1 + (size_t)s * 512 + dimbase);
#pragma unroll
    for (int j = 0; j < 8; ++j) acc[j] = fmaf(w, bf2f((u16)hv[j]), acc[j]);
    s = snext;
  }

  float inv = invden[(size_t)node * 4 + head];
  u16* orow = out + (size_t)node * 512 + dimbase;
#pragma unroll
  for (int j = 0; j < 8; ++j) {
    float v = acc[j] * inv + b1[dimbase + j];
    v = v > 0.f ? v : expm1f(v);   // ELU between layers
    orow[j] = f2bf(v);
  }
}

// layer2: one wave per dst node, 64 dims, 1 head. Output f32 (+b2), no ELU.
__global__ __launch_bounds__(256) void agg2_kernel(
    const u16* __restrict__ h2, const float* __restrict__ alpha,
    const float* __restrict__ invden, const int* __restrict__ rowoff,
    const int* __restrict__ csr, const float* __restrict__ b2,
    float* __restrict__ out, int n)
{
  int node = (blockIdx.x * 256 + threadIdx.x) >> 6;
  int lane = threadIdx.x & 63;
  if (node >= n) return;
  int e0 = rowoff[node], e1 = rowoff[node + 1];

  float acc = 0.f;
  int s = (e0 < e1) ? csr[e0] : 0;
  for (int e = e0; e < e1; ++e) {
    int snext = (e + 1 < e1) ? csr[e + 1] : s;
    float w = alpha[e];
    acc = fmaf(w, bf2f(h2[(size_t)s * 64 + lane]), acc);
    s = snext;
  }
  out[(size_t)node * 64 + lane] = acc * invden[node] + b2[lane];
}

// ---------------- launch ----------------
extern "C" void kernel_launch(void* const* d_in, const int* in_sizes, int n_in,
                              void* d_out, int out_size, void* d_ws, size_t ws_size,
                              hipStream_t stream) {
  const float* x   = (const float*)d_in[0];
  const int*   ei  = (const int*)d_in[1];
  const float* W1  = (const float*)d_in[3];
  const float* a1s = (const float*)d_in[4];
  const float* a1d = (const float*)d_in[5];
  const float* b1  = (const float*)d_in[6];
  const float* W2  = (const float*)d_in[7];
  const float* a2s = (const float*)d_in[8];
  const float* a2d = (const float*)d_in[9];
  const float* b2  = (const float*)d_in[10];
  float* out = (float*)d_out;

  const int IN_DIM = 256, H1D1 = 512, D2 = 64;
  const int N = in_sizes[0] / IN_DIM;
  const int E = in_sizes[1] / 2;

  char* ws = (char*)d_ws;
  size_t off = 0;
  auto alloc = [&](size_t bytes) -> void* {
    void* p = ws + off;
    off += (bytes + 255) & ~(size_t)255;
    return p;
  };
  u16*  xb     = (u16*)alloc((size_t)N * IN_DIM * 2);
  u16*  w1t    = (u16*)alloc((size_t)H1D1 * IN_DIM * 2);
  u16*  w2t    = (u16*)alloc((size_t)D2 * H1D1 * 2);
  u16*  h1b    = (u16*)alloc((size_t)N * H1D1 * 2);
  float* as1   = (float*)alloc((size_t)N * 4 * 4);
  float* ad1   = (float*)alloc((size_t)N * 4 * 4);
  int*  cnt    = (int*)alloc((size_t)N * 4);
  int*  cursor = (int*)alloc((size_t)N * 4);
  int*  rowoff = (int*)alloc((size_t)(N + 1) * 4);
  int*  bsum   = (int*)alloc(256 * 4);
  int*  boff   = (int*)alloc(256 * 4);
  int*  csr    = (int*)alloc((size_t)(E + N) * 4);
  u16*  h1o    = (u16*)alloc((size_t)N * H1D1 * 2);
  u16*  h2b    = (u16*)alloc((size_t)N * D2 * 2);
  float* as2   = (float*)alloc((size_t)N * 4);
  float* ad2   = (float*)alloc((size_t)N * 4);
  float* inv1  = (float*)alloc((size_t)N * 4 * 4);
  float* inv2  = (float*)alloc((size_t)N * 4);
  (void)n_in; (void)out_size; (void)ws_size;

  // alpha buffers alias xb: xb (25.6 MB) is dead after gemm1; softmax1/2 run
  // strictly later in-stream, and each replay rewrites xb first. alpha1 is
  // (E+N)*4 f32 = 7.2 MB, alpha2 (E+N) f32 = 1.8 MB -> both fit.
  float* alpha1 = (float*)xb;
  float* alpha2 = (float*)(xb + (((size_t)(E + N) * 4 * 4 + 255) & ~(size_t)255) / 2);

  const int* esrc = ei;
  const int* edst = ei + E;

  hipMemsetAsync(cnt, 0, (size_t)N * 4, stream);

  f32_to_bf16_kernel<<<((long)N * IN_DIM / 4 + 255) / 256, 256, 0, stream>>>(x, xb, (long)N * IN_DIM);
  conv_transpose_kernel<<<(IN_DIM * H1D1 + 255) / 256, 256, 0, stream>>>(W1, w1t, IN_DIM, H1D1);
  conv_transpose_kernel<<<(H1D1 * D2 + 255) / 256, 256, 0, stream>>>(W2, w2t, H1D1, D2);

  dim3 g1((N + 127) / 128, H1D1 / 128);
  gemm_bf16_kernel<128, 128, 2, 2><<<g1, 256, 0, stream>>>(xb, w1t, h1b, N, H1D1, IN_DIM);

  alpha1_kernel<<<(N + 3) / 4, 256, 0, stream>>>(h1b, a1s, a1d, as1, ad1, N);

  deg_kernel<<<(E + 255) / 256, 256, 0, stream>>>(edst, cnt, E);
  int nsb = (N + 255) / 256;
  scan_a_kernel<<<nsb, 256, 0, stream>>>(cnt, bsum, N);
  scan_b_kernel<<<1, 256, 0, stream>>>(bsum, boff, nsb);
  scan_c_kernel<<<nsb, 256, 0, stream>>>(cnt, boff, rowoff, cursor, N);
  scatter_kernel<<<(E + N + 255) / 256, 256, 0, stream>>>(esrc, edst, cursor, csr, E, N);

  softmax1_kernel<<<(N + 255) / 256, 256, 0, stream>>>(as1, ad1, rowoff, csr, alpha1, inv1, N);
  agg1_kernel<<<(N + 3) / 4, 256, 0, stream>>>(h1b, alpha1, inv1, rowoff, csr, b1, h1o, N);

  dim3 g2((N + 127) / 128, 1);
  gemm_bf16_kernel<128, 64, 4, 1><<<g2, 256, 0, stream>>>(h1o, w2t, h2b, N, D2, H1D1);

  alpha2_kernel<<<(N + 3) / 4, 256, 0, stream>>>(h2b, a2s, a2d, as2, ad2, N);
  softmax2_kernel<<<(N + 255) / 256, 256, 0, stream>>>(as2, ad2, rowoff, csr, alpha2, inv2, N);
  agg2_kernel<<<(N + 3) / 4, 256, 0, stream>>>(h2b, alpha2, inv2, rowoff, csr, b2, out, N);
}

// Round 3
// 295.777 us; speedup vs baseline: 1.2189x; 1.0258x over previous
//
#include <hip/hip_runtime.h>
#include <cstdint>

typedef unsigned short u16;
typedef short bf16x8_t __attribute__((ext_vector_type(8)));
typedef float f32x4_t __attribute__((ext_vector_type(4)));

#define DEVFN __device__ __forceinline__

DEVFN u16 f2bf(float f) {
  unsigned u = __builtin_bit_cast(unsigned, f);
  u = (u + 0x7fffu + ((u >> 16) & 1u)) >> 16;
  return (u16)u;
}
DEVFN float bf2f(u16 s) {
  unsigned u = ((unsigned)s) << 16;
  return __builtin_bit_cast(float, u);
}
DEVFN float lrelu(float x) { return x > 0.f ? x : 0.2f * x; }

// global -> LDS direct copy, 16B per lane. LDS dest is wave-uniform base +
// lane*16 (HW rule); caller passes the wave's base, per-lane global src.
DEVFN void gload_lds16(const u16* g, u16* l) {
  __builtin_amdgcn_global_load_lds(
      (const __attribute__((address_space(1))) void*)g,
      (__attribute__((address_space(3))) void*)l, 16, 0, 0);
}

// ---------------- converts ----------------
__global__ void f32_to_bf16_kernel(const float* __restrict__ in, u16* __restrict__ out, long n) {
  long i = ((long)blockIdx.x * 256 + threadIdx.x) * 4;
  if (i + 4 <= n) {
    float4 v = *reinterpret_cast<const float4*>(in + i);
    uint2 pack;
    pack.x = (unsigned)f2bf(v.x) | ((unsigned)f2bf(v.y) << 16);
    pack.y = (unsigned)f2bf(v.z) | ((unsigned)f2bf(v.w) << 16);
    *reinterpret_cast<uint2*>(out + i) = pack;
  }
}

// in [K][M] row-major -> out [M][K] bf16
__global__ void conv_transpose_kernel(const float* __restrict__ in, u16* __restrict__ out, int K, int M) {
  int idx = blockIdx.x * 256 + threadIdx.x;
  if (idx >= K * M) return;
  int k = idx / M, m = idx % M;
  out[(size_t)m * K + k] = f2bf(in[idx]);
}

// ---------------- GEMM: A[M][K] bf16 @ BT[N][K] bf16 -> C[M][N] bf16 ----------------
// Staging via global_load_lds width=16: flat LDS byte offset (c*256+tid)*16
// maps to row = c*64 + tid>>2, col(u16) = (tid&3)*8 of the [.][32] tile.
template<int BM, int BN, int WROWS, int WCOLS>
__global__ __launch_bounds__(256) void gemm_bf16_kernel(
    const u16* __restrict__ A, const u16* __restrict__ BT, u16* __restrict__ C,
    int M, int N, int K)
{
  constexpr int BK = 32;
  constexpr int WM = BM / WROWS;
  constexpr int WN = BN / WCOLS;
  constexpr int MF = WM / 16;
  constexpr int NF = WN / 16;
  __shared__ __align__(16) u16 sA[BM][BK];
  __shared__ __align__(16) u16 sB[BN][BK];

  const int tid = threadIdx.x;
  const int lane = tid & 63;
  const int wid = tid >> 6;
  const int wr = wid / WCOLS, wc = wid % WCOLS;
  const int brow = blockIdx.x * BM;
  const int bcol = blockIdx.y * BN;

  f32x4_t acc[MF][NF];
#pragma unroll
  for (int i = 0; i < MF; ++i)
#pragma unroll
    for (int j = 0; j < NF; ++j) acc[i][j] = f32x4_t{0.f, 0.f, 0.f, 0.f};

  const int rsel = lane & 15;
  const int kgrp = (lane >> 4) * 8;
  const int ldrow = tid >> 2;       // 0..63
  const int ldcol = (tid & 3) * 8;  // u16 col: 0,8,16,24

  for (int k0 = 0; k0 < K; k0 += BK) {
#pragma unroll
    for (int c = 0; c < BM / 64; ++c) {
      int gr = brow + c * 64 + ldrow; gr = gr < M ? gr : M - 1;
      gload_lds16(A + (size_t)gr * K + k0 + ldcol,
                  &sA[0][0] + c * 2048 + wid * 512);
    }
#pragma unroll
    for (int c = 0; c < BN / 64; ++c) {
      int gb = bcol + c * 64 + ldrow;
      gload_lds16(BT + (size_t)gb * K + k0 + ldcol,
                  &sB[0][0] + c * 2048 + wid * 512);
    }
    __syncthreads();
    bf16x8_t af[MF], bfr[NF];
#pragma unroll
    for (int i = 0; i < MF; ++i)
      af[i] = *reinterpret_cast<const bf16x8_t*>(&sA[wr * WM + i * 16 + rsel][kgrp]);
#pragma unroll
    for (int j = 0; j < NF; ++j)
      bfr[j] = *reinterpret_cast<const bf16x8_t*>(&sB[wc * WN + j * 16 + rsel][kgrp]);
#pragma unroll
    for (int i = 0; i < MF; ++i)
#pragma unroll
      for (int j = 0; j < NF; ++j)
        acc[i][j] = __builtin_amdgcn_mfma_f32_16x16x32_bf16(af[i], bfr[j], acc[i][j], 0, 0, 0);
    __syncthreads();
  }

  const int crow0 = (lane >> 4) * 4;
  const int ccol = lane & 15;
#pragma unroll
  for (int i = 0; i < MF; ++i)
#pragma unroll
    for (int j = 0; j < NF; ++j)
#pragma unroll
      for (int r = 0; r < 4; ++r) {
        int gr = brow + wr * WM + i * 16 + crow0 + r;
        int gc = bcol + wc * WN + j * 16 + ccol;
        if (gr < M) C[(size_t)gr * N + gc] = f2bf(acc[i][j][r]);
      }
}

// ---------------- alpha dots ----------------
// layer1: h[N][512] bf16, heads=4, D=128
__global__ __launch_bounds__(256) void alpha1_kernel(
    const u16* __restrict__ h1, const float* __restrict__ a_s, const float* __restrict__ a_d,
    float* __restrict__ as1, float* __restrict__ ad1, int n)
{
  int node = (blockIdx.x * 256 + threadIdx.x) >> 6;
  int lane = threadIdx.x & 63;
  if (node >= n) return;
  int head = lane >> 4;
  int d0 = (lane & 15) * 8;
  bf16x8_t hv = *reinterpret_cast<const bf16x8_t*>(h1 + (size_t)node * 512 + lane * 8);
  const float* asrow = a_s + head * 128 + d0;
  const float* adrow = a_d + head * 128 + d0;
  float ps = 0.f, pd = 0.f;
#pragma unroll
  for (int j = 0; j < 8; ++j) {
    float v = bf2f((u16)hv[j]);
    ps = fmaf(v, asrow[j], ps);
    pd = fmaf(v, adrow[j], pd);
  }
#pragma unroll
  for (int d = 1; d < 16; d <<= 1) {
    ps += __shfl_xor(ps, d, 64);
    pd += __shfl_xor(pd, d, 64);
  }
  if ((lane & 15) == 0) {
    as1[(size_t)node * 4 + head] = ps;
    ad1[(size_t)node * 4 + head] = pd;
  }
}

// layer2: h[N][64] bf16, 1 head, D=64
__global__ __launch_bounds__(256) void alpha2_kernel(
    const u16* __restrict__ h2, const float* __restrict__ a_s, const float* __restrict__ a_d,
    float* __restrict__ as2, float* __restrict__ ad2, int n)
{
  int node = (blockIdx.x * 256 + threadIdx.x) >> 6;
  int lane = threadIdx.x & 63;
  if (node >= n) return;
  float v = bf2f(h2[(size_t)node * 64 + lane]);
  float ps = v * a_s[lane], pd = v * a_d[lane];
#pragma unroll
  for (int d = 1; d < 64; d <<= 1) {
    ps += __shfl_xor(ps, d, 64);
    pd += __shfl_xor(pd, d, 64);
  }
  if (lane == 0) { as2[node] = ps; ad2[node] = pd; }
}

// ---------------- CSR build ----------------
__global__ void deg_kernel(const int* __restrict__ dst, int* __restrict__ cnt, int e) {
  int i = blockIdx.x * 256 + threadIdx.x;
  if (i < e) atomicAdd(&cnt[dst[i]], 1);
}

DEVFN int block_scan_256(int v, int tid, int* wsum) {
#pragma unroll
  for (int d = 1; d < 64; d <<= 1) {
    int u = __shfl_up(v, d, 64);
    if ((tid & 63) >= d) v += u;
  }
  if ((tid & 63) == 63) wsum[tid >> 6] = v;
  __syncthreads();
  int add = 0;
#pragma unroll
  for (int w = 0; w < 4; ++w) add += (w < (tid >> 6)) ? wsum[w] : 0;
  __syncthreads();
  return v + add;
}

__global__ __launch_bounds__(256) void scan_a_kernel(const int* __restrict__ cnt, int* __restrict__ bsum, int n) {
  __shared__ int ws4[4];
  int i = blockIdx.x * 256 + threadIdx.x;
  int v = (i < n) ? cnt[i] + 1 : 0;   // +1 self loop
  int incl = block_scan_256(v, threadIdx.x, ws4);
  if (threadIdx.x == 255) bsum[blockIdx.x] = incl;
}

__global__ __launch_bounds__(256) void scan_b_kernel(const int* __restrict__ bsum, int* __restrict__ boff, int nb) {
  __shared__ int ws4[4];
  int v = (threadIdx.x < nb) ? bsum[threadIdx.x] : 0;
  int incl = block_scan_256(v, threadIdx.x, ws4);
  if (threadIdx.x < nb) boff[threadIdx.x] = incl - v;
}

__global__ __launch_bounds__(256) void scan_c_kernel(
    const int* __restrict__ cnt, const int* __restrict__ boff,
    int* __restrict__ rowoff, int* __restrict__ cursor, int n)
{
  __shared__ int ws4[4];
  int i = blockIdx.x * 256 + threadIdx.x;
  int v = (i < n) ? cnt[i] + 1 : 0;
  int incl = block_scan_256(v, threadIdx.x, ws4);
  int excl = incl - v;
  int off = boff[blockIdx.x] + excl;
  if (i < n) {
    rowoff[i] = off;
    cursor[i] = off;
    if (i == n - 1) rowoff[n] = off + v;
  }
}

__global__ void scatter_kernel(const int* __restrict__ srcs, const int* __restrict__ dsts,
                               int* __restrict__ cursor, int* __restrict__ csr, int e, int n) {
  int i = blockIdx.x * 256 + threadIdx.x;
  if (i >= e + n) return;
  int s, d;
  if (i < e) { s = srcs[i]; d = dsts[i]; }
  else       { s = i - e; d = s; }
  int pos = atomicAdd(&cursor[d], 1);
  csr[pos] = s;
}

// ---------------- softmax (per-node, hoisted out of the gather) ----------------
// layer1: one THREAD per node. Pass 1 gathers as1 once, caches lrelu vals in
// alpha; pass 2 re-reads alpha SEQUENTIALLY (coalesced-ish), writes ex back.
__global__ __launch_bounds__(256) void softmax1_kernel(
    const float* __restrict__ as1, const float* __restrict__ ad1,
    const int* __restrict__ rowoff, const int* __restrict__ csr,
    float* __restrict__ alpha, float* __restrict__ invden, int n)
{
  int node = blockIdx.x * 256 + threadIdx.x;
  if (node >= n) return;
  float4 adv = *reinterpret_cast<const float4*>(ad1 + (size_t)node * 4);
  int e0 = rowoff[node], e1 = rowoff[node + 1];

  float4 m = make_float4(-1e30f, -1e30f, -1e30f, -1e30f);
  for (int e = e0; e < e1; ++e) {
    int s = csr[e];
    float4 a = *reinterpret_cast<const float4*>(as1 + (size_t)s * 4);
    float4 l;
    l.x = lrelu(a.x + adv.x); m.x = fmaxf(m.x, l.x);
    l.y = lrelu(a.y + adv.y); m.y = fmaxf(m.y, l.y);
    l.z = lrelu(a.z + adv.z); m.z = fmaxf(m.z, l.z);
    l.w = lrelu(a.w + adv.w); m.w = fmaxf(m.w, l.w);
    *reinterpret_cast<float4*>(alpha + (size_t)e * 4) = l;
  }
  float4 den = make_float4(0.f, 0.f, 0.f, 0.f);
  for (int e = e0; e < e1; ++e) {
    float4 l = *reinterpret_cast<const float4*>(alpha + (size_t)e * 4);
    float4 ex;
    ex.x = expf(l.x - m.x); den.x += ex.x;
    ex.y = expf(l.y - m.y); den.y += ex.y;
    ex.z = expf(l.z - m.z); den.z += ex.z;
    ex.w = expf(l.w - m.w); den.w += ex.w;
    *reinterpret_cast<float4*>(alpha + (size_t)e * 4) = ex;
  }
  float4 inv;
  inv.x = 1.f / (den.x + 1e-16f);
  inv.y = 1.f / (den.y + 1e-16f);
  inv.z = 1.f / (den.z + 1e-16f);
  inv.w = 1.f / (den.w + 1e-16f);
  *reinterpret_cast<float4*>(invden + (size_t)node * 4) = inv;
}

// layer2: one thread per node, scalar (1 head), same two-pass caching
__global__ __launch_bounds__(256) void softmax2_kernel(
    const float* __restrict__ as2, const float* __restrict__ ad2,
    const int* __restrict__ rowoff, const int* __restrict__ csr,
    float* __restrict__ alpha, float* __restrict__ invden, int n)
{
  int node = blockIdx.x * 256 + threadIdx.x;
  if (node >= n) return;
  float adv = ad2[node];
  int e0 = rowoff[node], e1 = rowoff[node + 1];
  float m = -1e30f;
  for (int e = e0; e < e1; ++e) {
    float l = lrelu(as2[csr[e]] + adv);
    m = fmaxf(m, l);
    alpha[e] = l;
  }
  float den = 0.f;
  for (int e = e0; e < e1; ++e) {
    float ex = expf(alpha[e] - m);
    den += ex;
    alpha[e] = ex;
  }
  invden[node] = 1.f / (den + 1e-16f);
}

// ---------------- aggregation (pure weighted gather, 4x unrolled) ----------------
// layer1: one wave per dst node. lane covers dims [lane*8, lane*8+8), head = lane>>4.
__global__ __launch_bounds__(256) void agg1_kernel(
    const u16* __restrict__ h1, const float* __restrict__ alpha,
    const float* __restrict__ invden, const int* __restrict__ rowoff,
    const int* __restrict__ csr, const float* __restrict__ b1,
    u16* __restrict__ out, int n)
{
  int node = (blockIdx.x * 256 + threadIdx.x) >> 6;
  int lane = threadIdx.x & 63;
  if (node >= n) return;
  int head = lane >> 4;
  const int dimbase = lane * 8;
  int e0 = rowoff[node], e1 = rowoff[node + 1];

  float acc[8];
#pragma unroll
  for (int j = 0; j < 8; ++j) acc[j] = 0.f;

  int e = e0;
  for (; e + 4 <= e1; e += 4) {
    int s0 = csr[e], s1 = csr[e + 1], s2 = csr[e + 2], s3 = csr[e + 3];
    float w0 = alpha[(size_t)e * 4 + head];
    float w1 = alpha[(size_t)(e + 1) * 4 + head];
    float w2 = alpha[(size_t)(e + 2) * 4 + head];
    float w3 = alpha[(size_t)(e + 3) * 4 + head];
    bf16x8_t v0 = *reinterpret_cast<const bf16x8_t*>(h1 + (size_t)s0 * 512 + dimbase);
    bf16x8_t v1 = *reinterpret_cast<const bf16x8_t*>(h1 + (size_t)s1 * 512 + dimbase);
    bf16x8_t v2 = *reinterpret_cast<const bf16x8_t*>(h1 + (size_t)s2 * 512 + dimbase);
    bf16x8_t v3 = *reinterpret_cast<const bf16x8_t*>(h1 + (size_t)s3 * 512 + dimbase);
#pragma unroll
    for (int j = 0; j < 8; ++j) {
      acc[j] = fmaf(w0, bf2f((u16)v0[j]), acc[j]);
      acc[j] = fmaf(w1, bf2f((u16)v1[j]), acc[j]);
      acc[j] = fmaf(w2, bf2f((u16)v2[j]), acc[j]);
      acc[j] = fmaf(w3, bf2f((u16)v3[j]), acc[j]);
    }
  }
  for (; e < e1; ++e) {
    int s = csr[e];
    float w = alpha[(size_t)e * 4 + head];
    bf16x8_t hv = *reinterpret_cast<const bf16x8_t*>(h1 + (size_t)s * 512 + dimbase);
#pragma unroll
    for (int j = 0; j < 8; ++j) acc[j] = fmaf(w, bf2f((u16)hv[j]), acc[j]);
  }

  float inv = invden[(size_t)node * 4 + head];
  u16* orow = out + (size_t)node * 512 + dimbase;
#pragma unroll
  for (int j = 0; j < 8; ++j) {
    float v = acc[j] * inv + b1[dimbase + j];
    v = v > 0.f ? v : expm1f(v);   // ELU between layers
    orow[j] = f2bf(v);
  }
}

// layer2: one wave per dst node, 64 dims, 1 head. Output f32 (+b2), no ELU.
__global__ __launch_bounds__(256) void agg2_kernel(
    const u16* __restrict__ h2, const float* __restrict__ alpha,
    const float* __restrict__ invden, const int* __restrict__ rowoff,
    const int* __restrict__ csr, const float* __restrict__ b2,
    float* __restrict__ out, int n)
{
  int node = (blockIdx.x * 256 + threadIdx.x) >> 6;
  int lane = threadIdx.x & 63;
  if (node >= n) return;
  int e0 = rowoff[node], e1 = rowoff[node + 1];

  float acc = 0.f;
  int e = e0;
  for (; e + 4 <= e1; e += 4) {
    int s0 = csr[e], s1 = csr[e + 1], s2 = csr[e + 2], s3 = csr[e + 3];
    float w0 = alpha[e], w1 = alpha[e + 1], w2 = alpha[e + 2], w3 = alpha[e + 3];
    float x0 = bf2f(h2[(size_t)s0 * 64 + lane]);
    float x1 = bf2f(h2[(size_t)s1 * 64 + lane]);
    float x2 = bf2f(h2[(size_t)s2 * 64 + lane]);
    float x3 = bf2f(h2[(size_t)s3 * 64 + lane]);
    acc = fmaf(w0, x0, acc);
    acc = fmaf(w1, x1, acc);
    acc = fmaf(w2, x2, acc);
    acc = fmaf(w3, x3, acc);
  }
  for (; e < e1; ++e) {
    acc = fmaf(alpha[e], bf2f(h2[(size_t)csr[e] * 64 + lane]), acc);
  }
  out[(size_t)node * 64 + lane] = acc * invden[node] + b2[lane];
}

// ---------------- launch ----------------
extern "C" void kernel_launch(void* const* d_in, const int* in_sizes, int n_in,
                              void* d_out, int out_size, void* d_ws, size_t ws_size,
                              hipStream_t stream) {
  const float* x   = (const float*)d_in[0];
  const int*   ei  = (const int*)d_in[1];
  const float* W1  = (const float*)d_in[3];
  const float* a1s = (const float*)d_in[4];
  const float* a1d = (const float*)d_in[5];
  const float* b1  = (const float*)d_in[6];
  const float* W2  = (const float*)d_in[7];
  const float* a2s = (const float*)d_in[8];
  const float* a2d = (const float*)d_in[9];
  const float* b2  = (const float*)d_in[10];
  float* out = (float*)d_out;

  const int IN_DIM = 256, H1D1 = 512, D2 = 64;
  const int N = in_sizes[0] / IN_DIM;
  const int E = in_sizes[1] / 2;

  char* ws = (char*)d_ws;
  size_t off = 0;
  auto alloc = [&](size_t bytes) -> void* {
    void* p = ws + off;
    off += (bytes + 255) & ~(size_t)255;
    return p;
  };
  u16*  xb     = (u16*)alloc((size_t)N * IN_DIM * 2);
  u16*  w1t    = (u16*)alloc((size_t)H1D1 * IN_DIM * 2);
  u16*  w2t    = (u16*)alloc((size_t)D2 * H1D1 * 2);
  u16*  h1b    = (u16*)alloc((size_t)N * H1D1 * 2);
  float* as1   = (float*)alloc((size_t)N * 4 * 4);
  float* ad1   = (float*)alloc((size_t)N * 4 * 4);
  int*  cnt    = (int*)alloc((size_t)N * 4);
  int*  cursor = (int*)alloc((size_t)N * 4);
  int*  rowoff = (int*)alloc((size_t)(N + 1) * 4);
  int*  bsum   = (int*)alloc(256 * 4);
  int*  boff   = (int*)alloc(256 * 4);
  int*  csr    = (int*)alloc((size_t)(E + N) * 4);
  u16*  h1o    = (u16*)alloc((size_t)N * H1D1 * 2);
  u16*  h2b    = (u16*)alloc((size_t)N * D2 * 2);
  float* as2   = (float*)alloc((size_t)N * 4);
  float* ad2   = (float*)alloc((size_t)N * 4);
  float* inv1  = (float*)alloc((size_t)N * 4 * 4);
  float* inv2  = (float*)alloc((size_t)N * 4);
  (void)n_in; (void)out_size; (void)ws_size;

  // alpha buffers alias xb: xb (25.6 MB) is dead after gemm1; softmax1/2 run
  // strictly later in-stream, and each replay rewrites xb first. alpha1 is
  // (E+N)*4 f32 = 7.2 MB, alpha2 (E+N) f32 = 1.8 MB -> both fit.
  float* alpha1 = (float*)xb;
  float* alpha2 = (float*)(xb + (((size_t)(E + N) * 4 * 4 + 255) & ~(size_t)255) / 2);

  const int* esrc = ei;
  const int* edst = ei + E;

  hipMemsetAsync(cnt, 0, (size_t)N * 4, stream);

  f32_to_bf16_kernel<<<((long)N * IN_DIM / 4 + 255) / 256, 256, 0, stream>>>(x, xb, (long)N * IN_DIM);
  conv_transpose_kernel<<<(IN_DIM * H1D1 + 255) / 256, 256, 0, stream>>>(W1, w1t, IN_DIM, H1D1);
  conv_transpose_kernel<<<(H1D1 * D2 + 255) / 256, 256, 0, stream>>>(W2, w2t, H1D1, D2);

  dim3 g1((N + 127) / 128, H1D1 / 128);
  gemm_bf16_kernel<128, 128, 2, 2><<<g1, 256, 0, stream>>>(xb, w1t, h1b, N, H1D1, IN_DIM);

  alpha1_kernel<<<(N + 3) / 4, 256, 0, stream>>>(h1b, a1s, a1d, as1, ad1, N);

  deg_kernel<<<(E + 255) / 256, 256, 0, stream>>>(edst, cnt, E);
  int nsb = (N + 255) / 256;
  scan_a_kernel<<<nsb, 256, 0, stream>>>(cnt, bsum, N);
  scan_b_kernel<<<1, 256, 0, stream>>>(bsum, boff, nsb);
  scan_c_kernel<<<nsb, 256, 0, stream>>>(cnt, boff, rowoff, cursor, N);
  scatter_kernel<<<(E + N + 255) / 256, 256, 0, stream>>>(esrc, edst, cursor, csr, E, N);

  softmax1_kernel<<<(N + 255) / 256, 256, 0, stream>>>(as1, ad1, rowoff, csr, alpha1, inv1, N);
  agg1_kernel<<<(N + 3) / 4, 256, 0, stream>>>(h1b, alpha1, inv1, rowoff, csr, b1, h1o, N);

  dim3 g2((N + 127) / 128, 1);
  gemm_bf16_kernel<128, 64, 4, 1><<<g2, 256, 0, stream>>>(h1o, w2t, h2b, N, D2, H1D1);

  alpha2_kernel<<<(N + 3) / 4, 256, 0, stream>>>(h2b, a2s, a2d, as2, ad2, N);
  softmax2_kernel<<<(N + 255) / 256, 256, 0, stream>>>(as2, ad2, rowoff, csr, alpha2, inv2, N);
  agg2_kernel<<<(N + 3) / 4, 256, 0, stream>>>(h2b, alpha2, inv2, rowoff, csr, b2, out, N);
}